// Round 5
// baseline (3792.175 us; speedup 1.0000x reference)
//
#include <hip/hip_runtime.h>
#include <hip/hip_bf16.h>

// MultiLoRALinear: out = x@W.T + bias + (x @ A[idx]) @ B[idx]
// M=16384, K=4096, N=4096, rank 16.
//
// R5 changes vs R4 (theory: barrier-locked LDS<->MFMA alternation + area law):
//  - GEMM: 4 waves @ 128x128/wave (was 8 @ 128x64). LDS fragment traffic
//    96KB -> 64KB per K-tile per CU. acc 8x8 f32x4 (256 regs), 1 wave/SIMD,
//    __launch_bounds__(256,1).
//  - GEMM: dropped mid-phase barriers. Ring-4 LDS + one boundary
//    vmcnt(16)+s_barrier per tile bounds wave skew to <1 tile (stage t+3
//    targets buf[(t-1)&3]; no wave is in t-1 once any is in t). Staggered
//    waves overlap ds_read (one SIMD's wave) with MFMA (another's).
//  - Pre-pass rewrite: the fused per-thread A-gather was TA-bound (~400us
//    for 400MB). Now: plain streaming cvt for x and W + MFMA-based inter
//    (xb bf16 fragments x A-operand from fp32 with 4-segment broadcast loads).

#define M_TOT 16384
#define K_TOT 4096
#define N_TOT 4096
#define RANK 16
#define NT 128   // K_TOT / 32

typedef __attribute__((ext_vector_type(8))) short bf16x8;
typedef __attribute__((ext_vector_type(4))) float f32x4;

// ---------------- fp32 -> bf16 (round-to-nearest-even) ----------------
__device__ __forceinline__ unsigned short f2bf(float f) {
  unsigned int u = __builtin_bit_cast(unsigned int, f);
  u += 0x7fffu + ((u >> 16) & 1u);
  return (unsigned short)(u >> 16);
}

__global__ void cvt_bf16_kernel(const float* __restrict__ src,
                                unsigned short* __restrict__ dst, int n4) {
  int i = blockIdx.x * blockDim.x + threadIdx.x;
  const int stride = gridDim.x * blockDim.x;
  for (; i < n4; i += stride) {
    const float4 v = reinterpret_cast<const float4*>(src)[i];
    ushort4 o;
    o.x = f2bf(v.x); o.y = f2bf(v.y); o.z = f2bf(v.z); o.w = f2bf(v.w);
    reinterpret_cast<ushort4*>(dst)[i] = o;
  }
}

// ------------- inter = x @ A[slot] via MFMA (wave: 16 rows x r16) -------------
// A-operand: xb fragments (lane: row=l&15, k=(l>>4)*8..+8).
// B-operand: A[k][r] fp32 -> bf16 on the fly; lane l: col r=l&15,
// k=(l>>4)*8+j. Loads A[k*16 + r]: 16 consecutive r per 64B line -> 4-segment
// broadcast loads, A slot (256KB) is L2-resident and shared by 32 blocks.
__global__ __launch_bounds__(256) void lora_inter_mfma_kernel(
    const unsigned short* __restrict__ xb,
    const float* __restrict__ loraA,
    const int* __restrict__ idx,
    float* __restrict__ inter) {
  const int lane = threadIdx.x & 63;
  const int wv = threadIdx.x >> 6;
  const int m0 = blockIdx.x * 64 + wv * 16;
  const int slot = idx[m0 >> 11];
  const int q = lane >> 4;
  const int c = lane & 15;
  const unsigned short* __restrict__ xrow = xb + (size_t)(m0 + c) * K_TOT + q * 8;
  const float* __restrict__ Abase = loraA + (size_t)slot * K_TOT * RANK + c;

  f32x4 acc = (f32x4){0.f, 0.f, 0.f, 0.f};
#pragma unroll 4
  for (int kt = 0; kt < K_TOT; kt += 32) {
    const bf16x8 af = *reinterpret_cast<const bf16x8*>(xrow + kt);
    const float* __restrict__ Ak = Abase + (size_t)(kt + q * 8) * RANK;
    bf16x8 bfr;
#pragma unroll
    for (int j = 0; j < 8; ++j) bfr[j] = (short)f2bf(Ak[(size_t)j * RANK]);
    acc = __builtin_amdgcn_mfma_f32_16x16x32_bf16(af, bfr, acc, 0, 0, 0);
  }
  // C/D: col = lane&15 (= r), row = (lane>>4)*4 + i (= m within tile)
#pragma unroll
  for (int i = 0; i < 4; ++i)
    inter[(size_t)(m0 + q * 4 + i) * RANK + c] = acc[i];
}

// ---------------- deep-pipelined 256x256 GEMM, 4 waves ----------------
__device__ __forceinline__ void gload16(const void* g, void* l) {
  __builtin_amdgcn_global_load_lds(
      (const __attribute__((address_space(1))) unsigned int*)g,
      (__attribute__((address_space(3))) unsigned int*)l, 16, 0, 0);
}

__global__ __launch_bounds__(256, 1) void gemm_fused_kernel(
    const unsigned short* __restrict__ xb,   // [M][K] bf16
    const unsigned short* __restrict__ wb,   // [N][K] bf16
    const float* __restrict__ bias,          // [N]
    const float* __restrict__ inter,         // [M][RANK] f32
    const float* __restrict__ loraB,         // [32][RANK][N] f32
    const int* __restrict__ idx,             // [8]
    float* __restrict__ out) {               // [M][N] f32
  // ring-4 x (A: 256x32 bf16 = 16KB, B: 16KB) = 128 KiB
  __shared__ unsigned short lds[4][16384];
  char* ldsB = (char*)lds;

  const int tid = threadIdx.x;
  const int lane = tid & 63;
  const int wv = tid >> 6;     // 0..3
  const int wr = wv >> 1;      // M half
  const int wc = wv & 1;       // N half

  // XCD-aware bijective swizzle (1024 wgs, 8 XCDs)
  const int bid = ((blockIdx.x & 7) << 7) | (blockIdx.x >> 3);
  const int m0 = (bid >> 4) << 8;   // 64 M-panels
  const int n0 = (bid & 15) << 8;   // 16 N-panels

  // ---- staging (source pre-permuted by the swizzle involution) ----
  const int srow = tid >> 2;                        // 0..63
  const int sslot = (tid & 3) ^ ((srow >> 1) & 3);
  const unsigned short* xsrc = xb + (size_t)(m0 + srow) * K_TOT + sslot * 8;
  const unsigned short* wsrc = wb + (size_t)(n0 + srow) * K_TOT + sslot * 8;
  const int stg = wv << 10;   // wave-uniform base within 4KB row-group

#define STAGE_T(t)                                                          \
  do {                                                                      \
    const int _bo = (((t) & 3) << 15);                                      \
    const size_t _ko = (size_t)(t) * 32;                                    \
    gload16(xsrc + _ko,                       ldsB + _bo + 0     + stg);    \
    gload16(xsrc + (size_t)64  * K_TOT + _ko, ldsB + _bo + 4096  + stg);    \
    gload16(xsrc + (size_t)128 * K_TOT + _ko, ldsB + _bo + 8192  + stg);    \
    gload16(xsrc + (size_t)192 * K_TOT + _ko, ldsB + _bo + 12288 + stg);    \
    gload16(wsrc + _ko,                       ldsB + _bo + 16384 + stg);    \
    gload16(wsrc + (size_t)64  * K_TOT + _ko, ldsB + _bo + 20480 + stg);    \
    gload16(wsrc + (size_t)128 * K_TOT + _ko, ldsB + _bo + 24576 + stg);    \
    gload16(wsrc + (size_t)192 * K_TOT + _ko, ldsB + _bo + 28672 + stg);    \
  } while (0)

  // ---- ds_read byte offsets (swizzled: phys_slot = slot ^ ((row>>1)&3)) ----
  const int rl = lane & 15;
  const int q = lane >> 4;
  const int pslot = ((q ^ ((rl >> 1) & 3)) << 4);
  const int aoff = (wr * 128 + rl) * 64 + pslot;           // + mf*1024
  const int boff = 16384 + (wc * 128 + rl) * 64 + pslot;   // + nf*1024

  f32x4 acc[8][8];
#pragma unroll
  for (int i = 0; i < 8; ++i)
#pragma unroll
    for (int j = 0; j < 8; ++j) acc[i][j] = (f32x4){0.f, 0.f, 0.f, 0.f};

  // prologue: stage tiles 0,1,2 (24 loads); tile0 = 8 oldest
  STAGE_T(0); STAGE_T(1); STAGE_T(2);
  asm volatile("s_waitcnt vmcnt(16)" ::: "memory");
  __builtin_amdgcn_s_barrier();

#pragma unroll 1
  for (int t = 0; t < NT; ++t) {
    const char* Ab = ldsB + ((t & 3) << 15) + aoff;
    const char* Bb = ldsB + ((t & 3) << 15) + boff;
    if (t < NT - 3) STAGE_T(t + 3);

    bf16x8 af[8], bfr[8];
#pragma unroll
    for (int i = 0; i < 8; ++i)
      af[i] = *reinterpret_cast<const bf16x8*>(Ab + i * 1024);
#pragma unroll
    for (int i = 0; i < 8; ++i)
      bfr[i] = *reinterpret_cast<const bf16x8*>(Bb + i * 1024);
    asm volatile("s_waitcnt lgkmcnt(0)" ::: "memory");
    __builtin_amdgcn_sched_barrier(0);

#pragma unroll
    for (int mf = 0; mf < 8; ++mf)
#pragma unroll
      for (int nf = 0; nf < 8; ++nf)
        acc[mf][nf] = __builtin_amdgcn_mfma_f32_16x16x32_bf16(
            af[mf], bfr[nf], acc[mf][nf], 0, 0, 0);

    // boundary: tile t+1 must be resident before next iteration reads it
    if (t < NT - 3) {
      asm volatile("s_waitcnt vmcnt(16)" ::: "memory");
    } else if (t == NT - 3) {
      asm volatile("s_waitcnt vmcnt(8)" ::: "memory");
    } else {
      asm volatile("s_waitcnt vmcnt(0)" ::: "memory");
    }
    __builtin_amdgcn_s_barrier();
  }

  // ---------------- epilogue: + bias + inter @ B[slot] ----------------
  const int slot = idx[m0 >> 11];
  const float* __restrict__ Bmat = loraB + (size_t)slot * RANK * N_TOT;
  const int gn0 = n0 + wc * 128 + rl;

#pragma unroll
  for (int nf = 0; nf < 8; ++nf) {
    const int gn = gn0 + nf * 16;
    const float bv = bias[gn];
    float bcv[RANK];
#pragma unroll
    for (int p = 0; p < RANK; ++p) bcv[p] = Bmat[(size_t)p * N_TOT + gn];
#pragma unroll
    for (int mf = 0; mf < 8; ++mf) {
      const int gmb = m0 + wr * 128 + mf * 16 + (q << 2);
#pragma unroll
      for (int r = 0; r < 4; ++r) {
        const int gm = gmb + r;
        const float4* ivp = reinterpret_cast<const float4*>(inter + (size_t)gm * RANK);
        const float4 iv0 = ivp[0], iv1 = ivp[1], iv2 = ivp[2], iv3 = ivp[3];
        const float lora =
            iv0.x * bcv[0]  + iv0.y * bcv[1]  + iv0.z * bcv[2]  + iv0.w * bcv[3] +
            iv1.x * bcv[4]  + iv1.y * bcv[5]  + iv1.z * bcv[6]  + iv1.w * bcv[7] +
            iv2.x * bcv[8]  + iv2.y * bcv[9]  + iv2.z * bcv[10] + iv2.w * bcv[11] +
            iv3.x * bcv[12] + iv3.y * bcv[13] + iv3.z * bcv[14] + iv3.w * bcv[15];
        out[(size_t)gm * N_TOT + gn] = acc[mf][nf][r] + bv + lora;
      }
    }
  }
#undef STAGE_T
}

// ---------------- host launcher ----------------
extern "C" void kernel_launch(void* const* d_in, const int* in_sizes, int n_in,
                              void* d_out, int out_size, void* d_ws, size_t ws_size,
                              hipStream_t stream) {
  const float* x     = (const float*)d_in[0];  // [8,2048,4096]
  const float* w     = (const float*)d_in[1];  // [4096,4096]
  const float* bias  = (const float*)d_in[2];  // [4096]
  const float* loraA = (const float*)d_in[3];  // [32,4096,16]
  const float* loraB = (const float*)d_in[4];  // [32,16,4096]
  const int*   idx   = (const int*)d_in[5];    // [8]
  float* out = (float*)d_out;

  char* ws = (char*)d_ws;
  unsigned short* xb   = (unsigned short*)ws;                  // 134,217,728 B
  unsigned short* wbuf = (unsigned short*)(ws + 134217728);    //  33,554,432 B
  float* inter = (float*)(ws + 134217728 + 33554432);          //   1,048,576 B

  cvt_bf16_kernel<<<2048, 256, 0, stream>>>(x, xb, M_TOT * K_TOT / 4);
  cvt_bf16_kernel<<<1024, 256, 0, stream>>>(w, wbuf, N_TOT * K_TOT / 4);
  lora_inter_mfma_kernel<<<M_TOT / 64, 256, 0, stream>>>(xb, loraA, idx, inter);
  gemm_fused_kernel<<<(M_TOT / 256) * (N_TOT / 256), 256, 0, stream>>>(
      xb, wbuf, bias, inter, loraB, idx, out);
}

// Round 6
// 946.415 us; speedup vs baseline: 4.0069x; 4.0069x over previous
//
#include <hip/hip_runtime.h>
#include <hip/hip_bf16.h>

// MultiLoRALinear: out = x@W.T + bias + (x @ A[idx]) @ B[idx]
// M=16384, K=4096, N=4096, rank 16.
//
// R6 = R4's proven 8-wave geometry + R5's proven relaxed schedule:
//  - 8 waves (2Mx4N), wave-tile 128x64, acc[8][4] f32x4 = 128 regs (R4: no
//    spill, VGPR 120). R5's 4-wave/acc256 spilled (VGPR class cap 256).
//  - ONE barrier + counted vmcnt per K-tile (R5-validated): waves drift
//    within a tile, overlapping ds_read (one wave) with MFMA (other wave on
//    same SIMD). R4's 2 mid-phase barriers serialized LDS<->MFMA pipes
//    (tile = 1242 MFMA + 1152 LDS + sync ~= 2836 cyc, measured).
//  - Partial lgkmcnt(4): first 16 MFMA start while last 4 ds_reads land.
//  - T5 setprio around MFMA clusters; stage issued before ds_reads (T3).
//  - Pre-pass from R5 kept verbatim (~134 us total).

#define M_TOT 16384
#define K_TOT 4096
#define N_TOT 4096
#define RANK 16
#define NT 128   // K_TOT / 32

typedef __attribute__((ext_vector_type(8))) short bf16x8;
typedef __attribute__((ext_vector_type(4))) float f32x4;

// ---------------- fp32 -> bf16 (round-to-nearest-even) ----------------
__device__ __forceinline__ unsigned short f2bf(float f) {
  unsigned int u = __builtin_bit_cast(unsigned int, f);
  u += 0x7fffu + ((u >> 16) & 1u);
  return (unsigned short)(u >> 16);
}

__global__ void cvt_bf16_kernel(const float* __restrict__ src,
                                unsigned short* __restrict__ dst, int n4) {
  int i = blockIdx.x * blockDim.x + threadIdx.x;
  const int stride = gridDim.x * blockDim.x;
  for (; i < n4; i += stride) {
    const float4 v = reinterpret_cast<const float4*>(src)[i];
    ushort4 o;
    o.x = f2bf(v.x); o.y = f2bf(v.y); o.z = f2bf(v.z); o.w = f2bf(v.w);
    reinterpret_cast<ushort4*>(dst)[i] = o;
  }
}

// ------------- inter = x @ A[slot] via MFMA (wave: 16 rows x r16) -------------
__global__ __launch_bounds__(256) void lora_inter_mfma_kernel(
    const unsigned short* __restrict__ xb,
    const float* __restrict__ loraA,
    const int* __restrict__ idx,
    float* __restrict__ inter) {
  const int lane = threadIdx.x & 63;
  const int wv = threadIdx.x >> 6;
  const int m0 = blockIdx.x * 64 + wv * 16;
  const int slot = idx[m0 >> 11];
  const int q = lane >> 4;
  const int c = lane & 15;
  const unsigned short* __restrict__ xrow = xb + (size_t)(m0 + c) * K_TOT + q * 8;
  const float* __restrict__ Abase = loraA + (size_t)slot * K_TOT * RANK + c;

  f32x4 acc = (f32x4){0.f, 0.f, 0.f, 0.f};
#pragma unroll 4
  for (int kt = 0; kt < K_TOT; kt += 32) {
    const bf16x8 af = *reinterpret_cast<const bf16x8*>(xrow + kt);
    const float* __restrict__ Ak = Abase + (size_t)(kt + q * 8) * RANK;
    bf16x8 bfr;
#pragma unroll
    for (int j = 0; j < 8; ++j) bfr[j] = (short)f2bf(Ak[(size_t)j * RANK]);
    acc = __builtin_amdgcn_mfma_f32_16x16x32_bf16(af, bfr, acc, 0, 0, 0);
  }
#pragma unroll
  for (int i = 0; i < 4; ++i)
    inter[(size_t)(m0 + q * 4 + i) * RANK + c] = acc[i];
}

// ---------------- deep-pipelined 256x256 GEMM, 8 waves ----------------
__device__ __forceinline__ void gload16(const void* g, void* l) {
  __builtin_amdgcn_global_load_lds(
      (const __attribute__((address_space(1))) unsigned int*)g,
      (__attribute__((address_space(3))) unsigned int*)l, 16, 0, 0);
}

__global__ __launch_bounds__(512, 2) void gemm_fused_kernel(
    const unsigned short* __restrict__ xb,   // [M][K] bf16
    const unsigned short* __restrict__ wb,   // [N][K] bf16
    const float* __restrict__ bias,          // [N]
    const float* __restrict__ inter,         // [M][RANK] f32
    const float* __restrict__ loraB,         // [32][RANK][N] f32
    const int* __restrict__ idx,             // [8]
    float* __restrict__ out) {               // [M][N] f32
  // ring-4 x (A: 256x32 bf16 = 16KB, B: 16KB) = 128 KiB
  __shared__ unsigned short lds[4][16384];
  char* ldsB = (char*)lds;

  const int tid = threadIdx.x;
  const int lane = tid & 63;
  const int wv = tid >> 6;   // 0..7
  const int wr = wv >> 2;    // 0..1 (M half)
  const int wc = wv & 3;     // 0..3 (N quarter)

  // XCD-aware bijective swizzle: 1024 wgs, 8 XCDs, 128 per chunk
  const int bid = ((blockIdx.x & 7) << 7) | (blockIdx.x >> 3);
  const int m0 = (bid >> 4) << 8;   // 64 M-panels
  const int n0 = (bid & 15) << 8;   // 16 N-panels

  // ---- staging source (pre-permuted by the LDS swizzle involution) ----
  const int srow = tid >> 2;                        // 0..127
  const int sslot = (tid & 3) ^ ((srow >> 1) & 3);  // 16B slot within 64B row
  const unsigned short* xs0 = xb + (size_t)(m0 + srow) * K_TOT + sslot * 8;
  const unsigned short* xs1 = xs0 + (size_t)128 * K_TOT;
  const unsigned short* ws0 = wb + (size_t)(n0 + srow) * K_TOT + sslot * 8;
  const unsigned short* ws1 = ws0 + (size_t)128 * K_TOT;
  const int stg = wv << 10;  // wave-uniform LDS byte offset within region

#define STAGE_T(t)                                                 \
  do {                                                             \
    const int _bo = (((t) & 3) << 15);                             \
    const size_t _ko = (size_t)(t) * 32;                           \
    gload16(xs0 + _ko, ldsB + _bo + stg);                          \
    gload16(xs1 + _ko, ldsB + _bo + 8192 + stg);                   \
    gload16(ws0 + _ko, ldsB + _bo + 16384 + stg);                  \
    gload16(ws1 + _ko, ldsB + _bo + 24576 + stg);                  \
  } while (0)

  // ---- ds_read byte offsets (swizzled: phys_slot = slot ^ ((row>>1)&3)) ----
  const int rl = lane & 15;
  const int q = lane >> 4;
  const int pslot = ((q ^ ((rl >> 1) & 3)) << 4);
  const int aoff = (wr * 128 + rl) * 64 + pslot;           // + mf*1024
  const int boff = 16384 + (wc * 64 + rl) * 64 + pslot;    // + nf*1024

  f32x4 acc[8][4];
#pragma unroll
  for (int i = 0; i < 8; ++i)
#pragma unroll
    for (int j = 0; j < 4; ++j) acc[i][j] = (f32x4){0.f, 0.f, 0.f, 0.f};

  // prologue: stage tiles 0,1,2 (12 loads/thread); tile0 = 4 oldest
  STAGE_T(0); STAGE_T(1); STAGE_T(2);
  asm volatile("s_waitcnt vmcnt(8)" ::: "memory");
  __builtin_amdgcn_s_barrier();

#pragma unroll 1
  for (int t = 0; t < NT; ++t) {
    const char* Ab = ldsB + ((t & 3) << 15) + aoff;
    const char* Bb = ldsB + ((t & 3) << 15) + boff;
    if (t < NT - 3) STAGE_T(t + 3);

    bf16x8 a0[4], b0[4], a1[4];
#pragma unroll
    for (int i = 0; i < 4; ++i)
      a0[i] = *reinterpret_cast<const bf16x8*>(Ab + i * 1024);
#pragma unroll
    for (int i = 0; i < 4; ++i)
      b0[i] = *reinterpret_cast<const bf16x8*>(Bb + i * 1024);
#pragma unroll
    for (int i = 0; i < 4; ++i)
      a1[i] = *reinterpret_cast<const bf16x8*>(Ab + (4 + i) * 1024);

    // first 8 ds_reads (a0,b0) done; a1 still in flight
    asm volatile("s_waitcnt lgkmcnt(4)" ::: "memory");
    __builtin_amdgcn_sched_barrier(0);
    __builtin_amdgcn_s_setprio(1);
#pragma unroll
    for (int mf = 0; mf < 4; ++mf)
#pragma unroll
      for (int nf = 0; nf < 4; ++nf)
        acc[mf][nf] = __builtin_amdgcn_mfma_f32_16x16x32_bf16(
            a0[mf], b0[nf], acc[mf][nf], 0, 0, 0);
    __builtin_amdgcn_s_setprio(0);

    asm volatile("s_waitcnt lgkmcnt(0)" ::: "memory");
    __builtin_amdgcn_sched_barrier(0);
    __builtin_amdgcn_s_setprio(1);
#pragma unroll
    for (int mf = 0; mf < 4; ++mf)
#pragma unroll
      for (int nf = 0; nf < 4; ++nf)
        acc[4 + mf][nf] = __builtin_amdgcn_mfma_f32_16x16x32_bf16(
            a1[mf], b0[nf], acc[4 + mf][nf], 0, 0, 0);
    __builtin_amdgcn_s_setprio(0);

    // tile boundary: guarantee tile t+1 resident before next iteration
    if (t < NT - 3) {
      asm volatile("s_waitcnt vmcnt(8)" ::: "memory");
    } else if (t == NT - 3) {
      asm volatile("s_waitcnt vmcnt(4)" ::: "memory");
    } else {
      asm volatile("s_waitcnt vmcnt(0)" ::: "memory");
    }
    __builtin_amdgcn_s_barrier();
  }

  // ---------------- epilogue: + bias + inter @ B[slot] ----------------
  const int slot = idx[m0 >> 11];
  const float* __restrict__ Bmat = loraB + (size_t)slot * RANK * N_TOT;
  const int gn0 = n0 + wc * 64 + rl;

#pragma unroll
  for (int nf = 0; nf < 4; ++nf) {
    const int gn = gn0 + nf * 16;
    const float bv = bias[gn];
    float bcv[RANK];
#pragma unroll
    for (int p = 0; p < RANK; ++p) bcv[p] = Bmat[(size_t)p * N_TOT + gn];
#pragma unroll
    for (int mf = 0; mf < 8; ++mf) {
      const int gmb = m0 + wr * 128 + mf * 16 + (q << 2);
#pragma unroll
      for (int r = 0; r < 4; ++r) {
        const int gm = gmb + r;
        const float4* ivp = reinterpret_cast<const float4*>(inter + (size_t)gm * RANK);
        const float4 iv0 = ivp[0], iv1 = ivp[1], iv2 = ivp[2], iv3 = ivp[3];
        const float lora =
            iv0.x * bcv[0]  + iv0.y * bcv[1]  + iv0.z * bcv[2]  + iv0.w * bcv[3] +
            iv1.x * bcv[4]  + iv1.y * bcv[5]  + iv1.z * bcv[6]  + iv1.w * bcv[7] +
            iv2.x * bcv[8]  + iv2.y * bcv[9]  + iv2.z * bcv[10] + iv2.w * bcv[11] +
            iv3.x * bcv[12] + iv3.y * bcv[13] + iv3.z * bcv[14] + iv3.w * bcv[15];
        out[(size_t)gm * N_TOT + gn] = acc[mf][nf][r] + bv + lora;
      }
    }
  }
#undef STAGE_T
}

// ---------------- host launcher ----------------
extern "C" void kernel_launch(void* const* d_in, const int* in_sizes, int n_in,
                              void* d_out, int out_size, void* d_ws, size_t ws_size,
                              hipStream_t stream) {
  const float* x     = (const float*)d_in[0];  // [8,2048,4096]
  const float* w     = (const float*)d_in[1];  // [4096,4096]
  const float* bias  = (const float*)d_in[2];  // [4096]
  const float* loraA = (const float*)d_in[3];  // [32,4096,16]
  const float* loraB = (const float*)d_in[4];  // [32,16,4096]
  const int*   idx   = (const int*)d_in[5];    // [8]
  float* out = (float*)d_out;

  char* ws = (char*)d_ws;
  unsigned short* xb   = (unsigned short*)ws;                  // 134,217,728 B
  unsigned short* wbuf = (unsigned short*)(ws + 134217728);    //  33,554,432 B
  float* inter = (float*)(ws + 134217728 + 33554432);          //   1,048,576 B

  cvt_bf16_kernel<<<2048, 256, 0, stream>>>(x, xb, M_TOT * K_TOT / 4);
  cvt_bf16_kernel<<<1024, 256, 0, stream>>>(w, wbuf, N_TOT * K_TOT / 4);
  lora_inter_mfma_kernel<<<M_TOT / 64, 256, 0, stream>>>(xb, loraA, idx, inter);
  gemm_fused_kernel<<<(M_TOT / 256) * (N_TOT / 256), 512, 0, stream>>>(
      xb, wbuf, bias, inter, loraB, idx, out);
}